// Round 3
// baseline (92.640 us; speedup 1.0000x reference)
//
#include <hip/hip_runtime.h>

// C = diag(A) @ B : scale row i of B by A[i].
// N=16384, M=4096, fp32. Memory-bound streaming: 537 MB/call.
// Floor at measured copy ceiling (6.29 TB/s, 1:1 R:W) = 85.4 us.
//
// Round-2 structure (row-block, scalar A, ILP-4) reached 91.9 us (5.84 TB/s).
// This round: 2 rows per iteration -> 8 float4 loads in flight per wave
// (deeper MLP over HBM turnaround), A as aligned float2 scalar pair,
// half the loop iterations -> half the inter-row issue bubbles.

typedef float fvec4 __attribute__((ext_vector_type(4)));

__global__ __launch_bounds__(256) void rowscale_rows2_kernel(
    const float* __restrict__ A,
    const fvec4* __restrict__ B,
    fvec4* __restrict__ C,
    unsigned int npairs,        // nrows/2
    unsigned int vec_per_row)   // = M/4 (fast path assumes 1024)
{
    const unsigned int tid = threadIdx.x;
    for (unsigned int p = blockIdx.x; p < npairs; p += gridDim.x) {
        const unsigned int row = p * 2u;
        // aligned float2 scalar load of A[row], A[row+1] (row even)
        const float2 a2 = *reinterpret_cast<const float2*>(A + row);
        const float a0 = a2.x;
        const float a1 = a2.y;
        const unsigned int base0 = row * vec_per_row;
        const fvec4* b0p = B + base0;
        fvec4* c0p = C + base0;
        const fvec4* b1p = b0p + vec_per_row;
        fvec4* c1p = c0p + vec_per_row;

        if (vec_per_row == 1024u) {
            // 8 loads issued back-to-back, then 8 stores
            fvec4 x0 = __builtin_nontemporal_load(&b0p[tid]);
            fvec4 x1 = __builtin_nontemporal_load(&b0p[tid + 256u]);
            fvec4 x2 = __builtin_nontemporal_load(&b0p[tid + 512u]);
            fvec4 x3 = __builtin_nontemporal_load(&b0p[tid + 768u]);
            fvec4 y0 = __builtin_nontemporal_load(&b1p[tid]);
            fvec4 y1 = __builtin_nontemporal_load(&b1p[tid + 256u]);
            fvec4 y2 = __builtin_nontemporal_load(&b1p[tid + 512u]);
            fvec4 y3 = __builtin_nontemporal_load(&b1p[tid + 768u]);
            __builtin_nontemporal_store(a0 * x0, &c0p[tid]);
            __builtin_nontemporal_store(a0 * x1, &c0p[tid + 256u]);
            __builtin_nontemporal_store(a0 * x2, &c0p[tid + 512u]);
            __builtin_nontemporal_store(a0 * x3, &c0p[tid + 768u]);
            __builtin_nontemporal_store(a1 * y0, &c1p[tid]);
            __builtin_nontemporal_store(a1 * y1, &c1p[tid + 256u]);
            __builtin_nontemporal_store(a1 * y2, &c1p[tid + 512u]);
            __builtin_nontemporal_store(a1 * y3, &c1p[tid + 768u]);
        } else {
            for (unsigned int j = tid; j < vec_per_row; j += blockDim.x) {
                __builtin_nontemporal_store(a0 * __builtin_nontemporal_load(&b0p[j]), &c0p[j]);
                __builtin_nontemporal_store(a1 * __builtin_nontemporal_load(&b1p[j]), &c1p[j]);
            }
        }
    }
}

// Odd-row fallback (not expected: N=16384 is even)
__global__ __launch_bounds__(256) void rowscale_rows_kernel(
    const float* __restrict__ A,
    const fvec4* __restrict__ B,
    fvec4* __restrict__ C,
    unsigned int nrows,
    unsigned int vec_per_row)
{
    const unsigned int tid = threadIdx.x;
    for (unsigned int row = blockIdx.x; row < nrows; row += gridDim.x) {
        const float a = A[row];
        const unsigned int base = row * vec_per_row;
        const fvec4* brow = B + base;
        fvec4* crow = C + base;
        for (unsigned int j = tid; j < vec_per_row; j += blockDim.x) {
            __builtin_nontemporal_store(a * __builtin_nontemporal_load(&brow[j]), &crow[j]);
        }
    }
}

extern "C" void kernel_launch(void* const* d_in, const int* in_sizes, int n_in,
                              void* d_out, int out_size, void* d_ws, size_t ws_size,
                              hipStream_t stream) {
    const float* A = (const float*)d_in[0];
    const fvec4* B = (const fvec4*)d_in[1];
    fvec4* C = (fvec4*)d_out;

    const unsigned int N = (unsigned int)in_sizes[0];
    const unsigned int total = (unsigned int)in_sizes[1];   // N*M
    const unsigned int M = total / N;
    const unsigned int vec_per_row = M / 4;

    const int block = 256;

    if ((N & 1u) == 0u && vec_per_row == 1024u) {
        const unsigned int npairs = N / 2u;                 // 8192
        unsigned int grid = npairs < 2048u ? npairs : 2048u; // 4 pairs/block
        rowscale_rows2_kernel<<<grid, block, 0, stream>>>(A, B, C, npairs, vec_per_row);
    } else {
        unsigned int grid = N < 4096u ? N : 4096u;
        rowscale_rows_kernel<<<grid, block, 0, stream>>>(A, B, C, N, vec_per_row);
    }
}